// Round 4
// baseline (1855.184 us; speedup 1.0000x reference)
//
#include <hip/hip_runtime.h>
#include <cmath>

#define WS 11
#define TILE 32                    // output tile: 32 x 32
#define HTILE 16                   // rows per half-pass
#define IN_TILE (TILE + WS - 1)    // 42 input rows
#define PADW 44                    // row stride (floats): 16B-aligned, bank skew 12
#define IMH 512
#define IMW 512
#define OH 502
#define OW 502
#define NPLANES 96                 // 32 * 3
#define GX 16
#define GY 16
#define NBLK (GX * GY * NPLANES)   // 24576
#define NOUT ((long long)NPLANES * OH * OW)  // 24192384

struct GaussW { float g[WS]; };

// ---------------- kernel 1: range-detection flags over img1 ----------------
__global__ __launch_bounds__(256) void flags_kernel(const float* __restrict__ img1,
                                                    unsigned* __restrict__ flags,
                                                    int n4) {
    int idx = blockIdx.x * blockDim.x + threadIdx.x;
    int stride = gridDim.x * blockDim.x;
    int gt = 0, lt = 0;
    const float4* p = reinterpret_cast<const float4*>(img1);
    for (int i = idx; i < n4; i += stride) {
        float4 v = p[i];
        gt |= (v.x > 128.f) | (v.y > 128.f) | (v.z > 128.f) | (v.w > 128.f);
        lt |= (v.x < -0.5f) | (v.y < -0.5f) | (v.z < -0.5f) | (v.w < -0.5f);
    }
    if (gt) atomicOr(&flags[0], 1u);
    if (lt) atomicOr(&flags[1], 1u);
}

// ---------------- kernel 2: tiled separable SSIM, half-tile vv ----------------
// LDS: s1/s2 staging (14.8 KB) + vv for 16 rows (14.1 KB) = 28.9 KB -> 5 blocks/CU.
__global__ __launch_bounds__(256, 5) void ssim_kernel(const float* __restrict__ img1,
                                                      const float* __restrict__ img2,
                                                      const unsigned* __restrict__ flags,
                                                      double* __restrict__ sum_out,
                                                      double* __restrict__ partials,
                                                      int use_partials,
                                                      GaussW gw) {
    __shared__ float s1[IN_TILE][PADW];      // 42 x 44
    __shared__ float s2[IN_TILE][PADW];
    __shared__ float vv[5][HTILE][PADW];     // 5 x 16 x 44
    __shared__ float wsum[4];

    const int plane = blockIdx.z;
    const int tx0 = blockIdx.x * TILE;
    const int ty0 = blockIdx.y * TILE;
    const float* p1 = img1 + (size_t)plane * (IMH * IMW);
    const float* p2 = img2 + (size_t)plane * (IMH * IMW);
    const int tid = threadIdx.x;

    // ---- stage halo tiles (float4 groups: 42 rows x 11 groups, zero-fill OOB) ----
    for (int i = tid; i < IN_TILE * 11; i += 256) {
        int r = i / 11, cg = i - r * 11;
        int gr = ty0 + r, gc = tx0 + cg * 4;
        float4 a = make_float4(0.f, 0.f, 0.f, 0.f);
        float4 b = make_float4(0.f, 0.f, 0.f, 0.f);
        if (gr < IMH) {
            const float* r1 = p1 + (size_t)gr * IMW;
            const float* r2 = p2 + (size_t)gr * IMW;
            if (gc + 3 < IMW) {
                a = *reinterpret_cast<const float4*>(r1 + gc);
                b = *reinterpret_cast<const float4*>(r2 + gc);
            } else {
                float ta[4] = {0.f, 0.f, 0.f, 0.f};
                float tb[4] = {0.f, 0.f, 0.f, 0.f};
                #pragma unroll
                for (int j = 0; j < 4; ++j) {
                    int c = gc + j;
                    if (c < IMW) { ta[j] = r1[c]; tb[j] = r2[c]; }
                }
                a = make_float4(ta[0], ta[1], ta[2], ta[3]);
                b = make_float4(tb[0], tb[1], tb[2], tb[3]);
            }
        }
        *reinterpret_cast<float4*>(&s1[r][cg * 4]) = a;
        *reinterpret_cast<float4*>(&s2[r][cg * 4]) = b;
    }
    __syncthreads();

    // ---- constants from range flags ----
    float maxv = flags[0] ? 255.f : 1.f;
    float minv = flags[1] ? -1.f : 0.f;
    float L = maxv - minv;
    float C1 = (0.01f * L) * (0.01f * L);
    float C2 = (0.03f * L) * (0.03f * L);

    float local = 0.f;

    #pragma unroll
    for (int h = 0; h < 2; ++h) {
        // ---- vertical Gaussian pass: 16 rows x 11 float4 col-groups = 176 items ----
        if (tid < HTILE * 11) {
            int r = tid / 11, cg = tid - r * 11;
            int sr = h * HTILE + r;          // starting input row within s-tile
            float m1[4] = {0,0,0,0}, m2[4] = {0,0,0,0};
            float q1[4] = {0,0,0,0}, q2[4] = {0,0,0,0}, q12[4] = {0,0,0,0};
            #pragma unroll
            for (int k = 0; k < WS; ++k) {
                float w = gw.g[k];
                float4 a4 = *reinterpret_cast<const float4*>(&s1[sr + k][cg * 4]);
                float4 b4 = *reinterpret_cast<const float4*>(&s2[sr + k][cg * 4]);
                float a[4] = {a4.x, a4.y, a4.z, a4.w};
                float b[4] = {b4.x, b4.y, b4.z, b4.w};
                #pragma unroll
                for (int j = 0; j < 4; ++j) {
                    m1[j]  += w * a[j];
                    m2[j]  += w * b[j];
                    q1[j]  += w * (a[j] * a[j]);
                    q2[j]  += w * (b[j] * b[j]);
                    q12[j] += w * (a[j] * b[j]);
                }
            }
            *reinterpret_cast<float4*>(&vv[0][r][cg * 4]) = make_float4(m1[0], m1[1], m1[2], m1[3]);
            *reinterpret_cast<float4*>(&vv[1][r][cg * 4]) = make_float4(m2[0], m2[1], m2[2], m2[3]);
            *reinterpret_cast<float4*>(&vv[2][r][cg * 4]) = make_float4(q1[0], q1[1], q1[2], q1[3]);
            *reinterpret_cast<float4*>(&vv[3][r][cg * 4]) = make_float4(q2[0], q2[1], q2[2], q2[3]);
            *reinterpret_cast<float4*>(&vv[4][r][cg * 4]) = make_float4(q12[0], q12[1], q12[2], q12[3]);
        }
        __syncthreads();

        // ---- horizontal pass: 16 rows x 16 col-pairs, 2 outputs/thread ----
        {
            const int r = tid >> 4;          // 0..15
            const int oc0 = (tid & 15) * 2;  // block-relative output col (even)
            const int base = oc0 & ~3;       // aligned window base (covers oc0..oc0+13)
            const int off = oc0 - base;      // 0 or 2
            float mu1[2], mu2[2], x2[2], y2[2], xy[2];
            #pragma unroll
            for (int q = 0; q < 5; ++q) {
                float w[16];
                #pragma unroll
                for (int t = 0; t < 4; ++t) {
                    float4 v = *reinterpret_cast<const float4*>(&vv[q][r][base + t * 4]);
                    w[t*4+0] = v.x; w[t*4+1] = v.y; w[t*4+2] = v.z; w[t*4+3] = v.w;
                }
                float* acc = (q == 0) ? mu1 : (q == 1) ? mu2 : (q == 2) ? x2 : (q == 3) ? y2 : xy;
                #pragma unroll
                for (int j = 0; j < 2; ++j) {
                    float s = 0.f;
                    #pragma unroll
                    for (int k = 0; k < WS; ++k) s += gw.g[k] * w[off + j + k];
                    acc[j] = s;
                }
            }
            const int oy = ty0 + h * HTILE + r;
            #pragma unroll
            for (int j = 0; j < 2; ++j) {
                int ox = tx0 + oc0 + j;
                if (oy < OH && ox < OW) {
                    float mu1s = mu1[j] * mu1[j], mu2s = mu2[j] * mu2[j], mu12 = mu1[j] * mu2[j];
                    float sg1 = x2[j] - mu1s, sg2 = y2[j] - mu2s, sg12 = xy[j] - mu12;
                    float v1 = 2.f * sg12 + C2;
                    float v2 = sg1 + sg2 + C2;
                    float num = (2.f * mu12 + C1) * v1;
                    float den = (mu1s + mu2s + C1) * v2;
                    float rc = __builtin_amdgcn_rcpf(den);
                    rc = rc * (2.0f - den * rc);   // 1 Newton step
                    local += num * rc;
                }
            }
        }
        __syncthreads();   // before next half overwrites vv (and harmless after h=1)
    }

    // ---- block reduction ----
    #pragma unroll
    for (int off = 32; off > 0; off >>= 1)
        local += __shfl_down(local, off, 64);

    int wave = tid >> 6, lane = tid & 63;
    if (lane == 0) wsum[wave] = local;
    __syncthreads();
    if (tid == 0) {
        double t = (double)wsum[0] + (double)wsum[1] + (double)wsum[2] + (double)wsum[3];
        if (use_partials) {
            int bid = (blockIdx.z * gridDim.y + blockIdx.y) * gridDim.x + blockIdx.x;
            partials[bid] = t;
        } else {
            atomicAdd(sum_out, t);
        }
    }
}

// ---------------- kernel 3: final reduce + mean ----------------
__global__ __launch_bounds__(256) void reduce_kernel(const double* __restrict__ sum,
                                                     const double* __restrict__ partials,
                                                     int use_partials,
                                                     float* __restrict__ out) {
    if (use_partials) {
        double local = 0.0;
        for (int i = threadIdx.x; i < NBLK; i += 256) local += partials[i];
        #pragma unroll
        for (int off = 32; off > 0; off >>= 1)
            local += __shfl_down(local, off, 64);
        __shared__ double ws2[4];
        int wave = threadIdx.x >> 6, lane = threadIdx.x & 63;
        if (lane == 0) ws2[wave] = local;
        __syncthreads();
        if (threadIdx.x == 0)
            out[0] = (float)((ws2[0] + ws2[1] + ws2[2] + ws2[3]) / (double)NOUT);
    } else {
        if (threadIdx.x == 0) out[0] = (float)(sum[0] / (double)NOUT);
    }
}

extern "C" void kernel_launch(void* const* d_in, const int* in_sizes, int n_in,
                              void* d_out, int out_size, void* d_ws, size_t ws_size,
                              hipStream_t stream) {
    const float* img1 = (const float*)d_in[0];
    const float* img2 = (const float*)d_in[1];
    float* out = (float*)d_out;

    // ws layout: [0..7] flags, [8..15] double sum, [16..] per-block partials
    unsigned* flags = (unsigned*)d_ws;
    double* sum = (double*)((char*)d_ws + 8);
    double* partials = (double*)((char*)d_ws + 16);
    int use_partials = (ws_size >= 16 + (size_t)NBLK * sizeof(double)) ? 1 : 0;

    hipMemsetAsync(d_ws, 0, 16, stream);

    // Gaussian taps (float64 math then cast, matching numpy reference)
    GaussW gw;
    {
        double g[WS], s = 0.0;
        for (int i = 0; i < WS; ++i) {
            double x = (double)(i - WS / 2);
            g[i] = exp(-(x * x) / (2.0 * 1.5 * 1.5));
            s += g[i];
        }
        for (int i = 0; i < WS; ++i) gw.g[i] = (float)(g[i] / s);
    }

    int n = in_sizes[0];           // 25,165,824 floats
    flags_kernel<<<2048, 256, 0, stream>>>(img1, flags, n / 4);

    dim3 grid(GX, GY, NPLANES);    // 16 x 16 x 96
    ssim_kernel<<<grid, 256, 0, stream>>>(img1, img2, flags, sum, partials, use_partials, gw);

    reduce_kernel<<<1, 256, 0, stream>>>(sum, partials, use_partials, out);
}

// Round 5
// 251.304 us; speedup vs baseline: 7.3822x; 7.3822x over previous
//
#include <hip/hip_runtime.h>
#include <cmath>

#define WS 11
#define TILE 32                    // output tile: 32 x 32
#define IN_TILE (TILE + WS - 1)    // 42 input rows
#define PADW 44                    // row stride (floats): 16B-aligned
#define IMH 512
#define IMW 512
#define OH 502
#define OW 502
#define NPLANES 96                 // 32 * 3
#define TX 16                      // tiles in x
#define TY 16                      // tiles in y
#define NTILES (TX * TY * NPLANES) // 24576
#define TPB 8                      // tiles per block
#define NBLK (NTILES / TPB)        // 3072
#define NOUT ((long long)NPLANES * OH * OW)  // 24192384

struct GaussW { float g[WS]; };

// ---------------- kernel 1: range-detection flags over img1 ----------------
__global__ __launch_bounds__(256) void flags_kernel(const float* __restrict__ img1,
                                                    unsigned* __restrict__ flags,
                                                    int n4) {
    int idx = blockIdx.x * blockDim.x + threadIdx.x;
    int stride = gridDim.x * blockDim.x;
    int gt = 0, lt = 0;
    const float4* p = reinterpret_cast<const float4*>(img1);
    for (int i = idx; i < n4; i += stride) {
        float4 v = p[i];
        gt |= (v.x > 128.f) | (v.y > 128.f) | (v.z > 128.f) | (v.w > 128.f);
        lt |= (v.x < -0.5f) | (v.y < -0.5f) | (v.z < -0.5f) | (v.w < -0.5f);
    }
    if (gt) atomicOr(&flags[0], 1u);
    if (lt) atomicOr(&flags[1], 1u);
}

// ---------------- kernel 2: multi-tile separable SSIM ----------------
// R2 structure (LDS staging + vv), but each block processes TPB tiles
// sequentially so CUs stay saturated (avoids the short-block residency gap).
// LDS ~43 KB -> 3 blocks/CU; VGPR uncapped (~88, no spills).
__global__ __launch_bounds__(256) void ssim_kernel(const float* __restrict__ img1,
                                                   const float* __restrict__ img2,
                                                   const unsigned* __restrict__ flags,
                                                   double* __restrict__ sum_out,
                                                   double* __restrict__ partials,
                                                   int use_partials,
                                                   GaussW gw) {
    __shared__ float s1[IN_TILE][PADW];      // 42 x 44
    __shared__ float s2[IN_TILE][PADW];
    __shared__ float vv[5][TILE][PADW];      // 5 x 32 x 44
    __shared__ float wsum[4];

    const int tid = threadIdx.x;

    // constants from range flags (uniform scalar loads)
    float maxv = flags[0] ? 255.f : 1.f;
    float minv = flags[1] ? -1.f : 0.f;
    float L = maxv - minv;
    float C1 = (0.01f * L) * (0.01f * L);
    float C2 = (0.03f * L) * (0.03f * L);

    float local = 0.f;

    for (int t = 0; t < TPB; ++t) {
        const int tileIdx = blockIdx.x * TPB + t;
        const int txi = tileIdx & (TX - 1);
        const int tyi = (tileIdx >> 4) & (TY - 1);
        const int plane = tileIdx >> 8;
        const int tx0 = txi * TILE;
        const int ty0 = tyi * TILE;
        const float* p1 = img1 + (size_t)plane * (IMH * IMW);
        const float* p2 = img2 + (size_t)plane * (IMH * IMW);

        // ---- stage halo tiles (float4 groups: 42 rows x 11 groups) ----
        for (int i = tid; i < IN_TILE * 11; i += 256) {
            int r = i / 11, cg = i - r * 11;
            int gr = ty0 + r, gc = tx0 + cg * 4;
            float4 a = make_float4(0.f, 0.f, 0.f, 0.f);
            float4 b = make_float4(0.f, 0.f, 0.f, 0.f);
            if (gr < IMH) {
                const float* r1 = p1 + (size_t)gr * IMW;
                const float* r2 = p2 + (size_t)gr * IMW;
                if (gc + 3 < IMW) {
                    a = *reinterpret_cast<const float4*>(r1 + gc);
                    b = *reinterpret_cast<const float4*>(r2 + gc);
                } else {
                    float ta[4] = {0.f, 0.f, 0.f, 0.f};
                    float tb[4] = {0.f, 0.f, 0.f, 0.f};
                    #pragma unroll
                    for (int j = 0; j < 4; ++j) {
                        int c = gc + j;
                        if (c < IMW) { ta[j] = r1[c]; tb[j] = r2[c]; }
                    }
                    a = make_float4(ta[0], ta[1], ta[2], ta[3]);
                    b = make_float4(tb[0], tb[1], tb[2], tb[3]);
                }
            }
            *reinterpret_cast<float4*>(&s1[r][cg * 4]) = a;
            *reinterpret_cast<float4*>(&s2[r][cg * 4]) = b;
        }
        __syncthreads();

        // ---- vertical Gaussian pass: 32 rows x 11 float4 col-groups ----
        for (int i = tid; i < TILE * 11; i += 256) {
            int r = i / 11, cg = i - r * 11;
            float m1[4] = {0,0,0,0}, m2[4] = {0,0,0,0};
            float q1[4] = {0,0,0,0}, q2[4] = {0,0,0,0}, q12[4] = {0,0,0,0};
            #pragma unroll
            for (int k = 0; k < WS; ++k) {
                float w = gw.g[k];
                float4 a4 = *reinterpret_cast<const float4*>(&s1[r + k][cg * 4]);
                float4 b4 = *reinterpret_cast<const float4*>(&s2[r + k][cg * 4]);
                float a[4] = {a4.x, a4.y, a4.z, a4.w};
                float b[4] = {b4.x, b4.y, b4.z, b4.w};
                #pragma unroll
                for (int j = 0; j < 4; ++j) {
                    m1[j]  += w * a[j];
                    m2[j]  += w * b[j];
                    q1[j]  += w * (a[j] * a[j]);
                    q2[j]  += w * (b[j] * b[j]);
                    q12[j] += w * (a[j] * b[j]);
                }
            }
            *reinterpret_cast<float4*>(&vv[0][r][cg * 4]) = make_float4(m1[0], m1[1], m1[2], m1[3]);
            *reinterpret_cast<float4*>(&vv[1][r][cg * 4]) = make_float4(m2[0], m2[1], m2[2], m2[3]);
            *reinterpret_cast<float4*>(&vv[2][r][cg * 4]) = make_float4(q1[0], q1[1], q1[2], q1[3]);
            *reinterpret_cast<float4*>(&vv[3][r][cg * 4]) = make_float4(q2[0], q2[1], q2[2], q2[3]);
            *reinterpret_cast<float4*>(&vv[4][r][cg * 4]) = make_float4(q12[0], q12[1], q12[2], q12[3]);
        }
        __syncthreads();

        // ---- horizontal pass: 256 threads, 4 outputs each ----
        {
            const int r = tid >> 3;          // 0..31
            const int cg = tid & 7;          // output cols cg*4 .. cg*4+3
            float mu1[4], mu2[4], x2[4], y2[4], xy[4];
            #pragma unroll
            for (int q = 0; q < 5; ++q) {
                float w[16];
                #pragma unroll
                for (int u = 0; u < 4; ++u) {
                    float4 v = *reinterpret_cast<const float4*>(&vv[q][r][cg * 4 + u * 4]);
                    w[u*4+0] = v.x; w[u*4+1] = v.y; w[u*4+2] = v.z; w[u*4+3] = v.w;
                }
                float* acc = (q == 0) ? mu1 : (q == 1) ? mu2 : (q == 2) ? x2 : (q == 3) ? y2 : xy;
                #pragma unroll
                for (int j = 0; j < 4; ++j) {
                    float s = 0.f;
                    #pragma unroll
                    for (int k = 0; k < WS; ++k) s += gw.g[k] * w[j + k];
                    acc[j] = s;
                }
            }
            const int oy = ty0 + r;
            #pragma unroll
            for (int j = 0; j < 4; ++j) {
                int ox = tx0 + cg * 4 + j;
                if (oy < OH && ox < OW) {
                    float mu1s = mu1[j] * mu1[j], mu2s = mu2[j] * mu2[j], mu12 = mu1[j] * mu2[j];
                    float sg1 = x2[j] - mu1s, sg2 = y2[j] - mu2s, sg12 = xy[j] - mu12;
                    float v1 = 2.f * sg12 + C2;
                    float v2 = sg1 + sg2 + C2;
                    float num = (2.f * mu12 + C1) * v1;
                    float den = (mu1s + mu2s + C1) * v2;
                    float rc = __builtin_amdgcn_rcpf(den);
                    rc = rc * (2.0f - den * rc);   // 1 Newton step
                    local += num * rc;
                }
            }
        }
        __syncthreads();   // protect s1/s2/vv reuse by next tile
    }

    // ---- block reduction (once, covers all TPB tiles) ----
    #pragma unroll
    for (int off = 32; off > 0; off >>= 1)
        local += __shfl_down(local, off, 64);

    int wave = tid >> 6, lane = tid & 63;
    if (lane == 0) wsum[wave] = local;
    __syncthreads();
    if (tid == 0) {
        double s = (double)wsum[0] + (double)wsum[1] + (double)wsum[2] + (double)wsum[3];
        if (use_partials) partials[blockIdx.x] = s;
        else atomicAdd(sum_out, s);
    }
}

// ---------------- kernel 3: final reduce + mean ----------------
__global__ __launch_bounds__(256) void reduce_kernel(const double* __restrict__ sum,
                                                     const double* __restrict__ partials,
                                                     int use_partials,
                                                     float* __restrict__ out) {
    if (use_partials) {
        double local = 0.0;
        for (int i = threadIdx.x; i < NBLK; i += 256) local += partials[i];
        #pragma unroll
        for (int off = 32; off > 0; off >>= 1)
            local += __shfl_down(local, off, 64);
        __shared__ double ws2[4];
        int wave = threadIdx.x >> 6, lane = threadIdx.x & 63;
        if (lane == 0) ws2[wave] = local;
        __syncthreads();
        if (threadIdx.x == 0)
            out[0] = (float)((ws2[0] + ws2[1] + ws2[2] + ws2[3]) / (double)NOUT);
    } else {
        if (threadIdx.x == 0) out[0] = (float)(sum[0] / (double)NOUT);
    }
}

extern "C" void kernel_launch(void* const* d_in, const int* in_sizes, int n_in,
                              void* d_out, int out_size, void* d_ws, size_t ws_size,
                              hipStream_t stream) {
    const float* img1 = (const float*)d_in[0];
    const float* img2 = (const float*)d_in[1];
    float* out = (float*)d_out;

    // ws layout: [0..7] flags, [8..15] double sum, [16..] per-block partials
    unsigned* flags = (unsigned*)d_ws;
    double* sum = (double*)((char*)d_ws + 8);
    double* partials = (double*)((char*)d_ws + 16);
    int use_partials = (ws_size >= 16 + (size_t)NBLK * sizeof(double)) ? 1 : 0;

    hipMemsetAsync(d_ws, 0, 16, stream);

    // Gaussian taps (float64 math then cast, matching numpy reference)
    GaussW gw;
    {
        double g[WS], s = 0.0;
        for (int i = 0; i < WS; ++i) {
            double x = (double)(i - WS / 2);
            g[i] = exp(-(x * x) / (2.0 * 1.5 * 1.5));
            s += g[i];
        }
        for (int i = 0; i < WS; ++i) gw.g[i] = (float)(g[i] / s);
    }

    int n = in_sizes[0];           // 25,165,824 floats
    flags_kernel<<<2048, 256, 0, stream>>>(img1, flags, n / 4);

    ssim_kernel<<<NBLK, 256, 0, stream>>>(img1, img2, flags, sum, partials, use_partials, gw);

    reduce_kernel<<<1, 256, 0, stream>>>(sum, partials, use_partials, out);
}

// Round 6
// 200.065 us; speedup vs baseline: 9.2729x; 1.2561x over previous
//
#include <hip/hip_runtime.h>
#include <cmath>

#define WS 11
#define IMH 512
#define IMW 512
#define OH 502
#define OW 502
#define NPLANES 96                 // 32 * 3
#define STRIPW 48                  // output cols per wave strip
#define STRIPH 64                  // output rows per wave strip (4 subs x 16)
#define SUBH 16                    // rows per lane
#define XSTRIPS 11                 // ceil(502/48)
#define YSTRIPS 8                  // ceil(502/64)
#define NTASKS (XSTRIPS * YSTRIPS * NPLANES)   // 8448
#define WPB 4                      // waves per block
#define NBLK (NTASKS / WPB)        // 2112
#define NOUT ((long long)NPLANES * OH * OW)    // 24192384

typedef float f32x4 __attribute__((ext_vector_type(4)));

struct GaussW { float g[WS]; };

// ---------------- kernel 1: range-detection flags over img1 ----------------
__global__ __launch_bounds__(256) void flags_kernel(const float* __restrict__ img1,
                                                    unsigned* __restrict__ flags,
                                                    int n4) {
    int idx = blockIdx.x * blockDim.x + threadIdx.x;
    int stride = gridDim.x * blockDim.x;
    int gt = 0, lt = 0;
    const float4* p = reinterpret_cast<const float4*>(img1);
    for (int i = idx; i < n4; i += stride) {
        float4 v = p[i];
        gt |= (v.x > 128.f) | (v.y > 128.f) | (v.z > 128.f) | (v.w > 128.f);
        lt |= (v.x < -0.5f) | (v.y < -0.5f) | (v.z < -0.5f) | (v.w < -0.5f);
    }
    if (gt) atomicOr(&flags[0], 1u);
    if (lt) atomicOr(&flags[1], 1u);
}

// ---------------- kernel 2: LDS-free register-ring SSIM ----------------
// Wave = one 48x64 output strip. Lane (g = lane&15, s = lane>>4) streams
// input col-group [4g..4g+3] down rows [16s .. 16s+25] with an 11-row
// register ring; vertical conv in regs, horizontal conv via __shfl from
// lanes +1,+2,+3. No __shared__, no barriers.
__global__ __launch_bounds__(256) void ssim_kernel(const float* __restrict__ img1,
                                                   const float* __restrict__ img2,
                                                   const unsigned* __restrict__ flags,
                                                   double* __restrict__ sum_out,
                                                   double* __restrict__ partials,
                                                   int use_partials,
                                                   GaussW gw) {
    const int tid = threadIdx.x;
    const int wave = tid >> 6;
    const int lane = tid & 63;
    const int g = lane & 15;           // col group within strip
    const int s = lane >> 4;           // row sub within strip

    const int task = blockIdx.x * WPB + wave;
    const int plane = task / (XSTRIPS * YSTRIPS);
    const int rem = task - plane * (XSTRIPS * YSTRIPS);
    const int wy = rem / XSTRIPS;
    const int wx = rem - wy * XSTRIPS;

    const float* p1 = img1 + (size_t)plane * (IMH * IMW);
    const float* p2 = img2 + (size_t)plane * (IMH * IMW);

    const int x0 = wx * STRIPW;                     // strip's output col base
    int colbase = x0 + 4 * g;                       // this lane's input col base
    colbase = colbase <= IMW - 4 ? colbase : IMW - 4;  // clamp (masked outputs only)
    const int ys = wy * STRIPH + s * SUBH;          // first output row of this sub

    // constants from range flags
    float maxv = flags[0] ? 255.f : 1.f;
    float minv = flags[1] ? -1.f : 0.f;
    float L = maxv - minv;
    float C1 = (0.01f * L) * (0.01f * L);
    float C2 = (0.03f * L) * (0.03f * L);

    // ---- prime the 11-row ring with rows ys .. ys+9 ----
    f32x4 ra[WS], rb[WS];
    #pragma unroll
    for (int k = 0; k < WS - 1; ++k) {
        int row = ys + k; row = row < IMH - 1 ? row : IMH - 1;
        const float* r1 = p1 + (size_t)row * IMW + colbase;
        const float* r2 = p2 + (size_t)row * IMW + colbase;
        ra[k] = *reinterpret_cast<const f32x4*>(r1);
        rb[k] = *reinterpret_cast<const f32x4*>(r2);
    }

    float local = 0.f;

    for (int i = 0; i < SUBH; ++i) {
        // load row ys+i+10 into ring slot 10
        {
            int row = ys + i + (WS - 1); row = row < IMH - 1 ? row : IMH - 1;
            const float* r1 = p1 + (size_t)row * IMW + colbase;
            const float* r2 = p2 + (size_t)row * IMW + colbase;
            ra[WS - 1] = *reinterpret_cast<const f32x4*>(r1);
            rb[WS - 1] = *reinterpret_cast<const f32x4*>(r2);
        }

        // ---- vertical 11-tap conv of the 5 quantities (registers only) ----
        f32x4 V0 = 0.f, V1 = 0.f, V2 = 0.f, V3 = 0.f, V4 = 0.f;
        #pragma unroll
        for (int k = 0; k < WS; ++k) {
            float w = gw.g[k];
            f32x4 a = ra[k], b = rb[k];
            V0 += w * a;
            V1 += w * b;
            V2 += w * (a * a);
            V3 += w * (b * b);
            V4 += w * (a * b);
        }

        // ---- shift ring ----
        #pragma unroll
        for (int k = 0; k < WS - 1; ++k) { ra[k] = ra[k + 1]; rb[k] = rb[k + 1]; }

        // ---- horizontal 11-tap conv via cross-lane shuffles ----
        // lane g needs V[4g .. 4g+13]: own 4 + 4 from g+1 + 4 from g+2 + 2 from g+3
        float hs[5][4];
        #pragma unroll
        for (int q = 0; q < 5; ++q) {
            f32x4 v = (q == 0) ? V0 : (q == 1) ? V1 : (q == 2) ? V2 : (q == 3) ? V3 : V4;
            float Wq[14];
            #pragma unroll
            for (int j = 0; j < 4; ++j) Wq[j] = v[j];
            #pragma unroll
            for (int j = 0; j < 4; ++j) Wq[4 + j]  = __shfl(v[j], lane + 1, 64);
            #pragma unroll
            for (int j = 0; j < 4; ++j) Wq[8 + j]  = __shfl(v[j], lane + 2, 64);
            #pragma unroll
            for (int j = 0; j < 2; ++j) Wq[12 + j] = __shfl(v[j], lane + 3, 64);
            #pragma unroll
            for (int c = 0; c < 4; ++c) {
                float acc = 0.f;
                #pragma unroll
                for (int k = 0; k < WS; ++k) acc += gw.g[k] * Wq[c + k];
                hs[q][c] = acc;
            }
        }

        // ---- SSIM map + masked accumulate ----
        const int oy = ys + i;
        #pragma unroll
        for (int c = 0; c < 4; ++c) {
            int ox = x0 + 4 * g + c;
            if (g < 12 && ox < OW && oy < OH) {
                float mu1 = hs[0][c], mu2 = hs[1][c];
                float mu1s = mu1 * mu1, mu2s = mu2 * mu2, mu12 = mu1 * mu2;
                float sg1 = hs[2][c] - mu1s, sg2 = hs[3][c] - mu2s, sg12 = hs[4][c] - mu12;
                float v1 = 2.f * sg12 + C2;
                float v2 = sg1 + sg2 + C2;
                float num = (2.f * mu12 + C1) * v1;
                float den = (mu1s + mu2s + C1) * v2;
                float rc = __builtin_amdgcn_rcpf(den);
                rc = rc * (2.0f - den * rc);   // 1 Newton step
                local += num * rc;
            }
        }
    }

    // ---- wave reduction -> one double per task ----
    #pragma unroll
    for (int off = 32; off > 0; off >>= 1)
        local += __shfl_down(local, off, 64);

    if (lane == 0) {
        if (use_partials) partials[task] = (double)local;
        else atomicAdd(sum_out, (double)local);
    }
}

// ---------------- kernel 3: final reduce + mean ----------------
__global__ __launch_bounds__(256) void reduce_kernel(const double* __restrict__ sum,
                                                     const double* __restrict__ partials,
                                                     int use_partials,
                                                     float* __restrict__ out) {
    if (use_partials) {
        double local = 0.0;
        for (int i = threadIdx.x; i < NTASKS; i += 256) local += partials[i];
        #pragma unroll
        for (int off = 32; off > 0; off >>= 1)
            local += __shfl_down(local, off, 64);
        __shared__ double ws2[4];
        int wave = threadIdx.x >> 6, lane = threadIdx.x & 63;
        if (lane == 0) ws2[wave] = local;
        __syncthreads();
        if (threadIdx.x == 0)
            out[0] = (float)((ws2[0] + ws2[1] + ws2[2] + ws2[3]) / (double)NOUT);
    } else {
        if (threadIdx.x == 0) out[0] = (float)(sum[0] / (double)NOUT);
    }
}

extern "C" void kernel_launch(void* const* d_in, const int* in_sizes, int n_in,
                              void* d_out, int out_size, void* d_ws, size_t ws_size,
                              hipStream_t stream) {
    const float* img1 = (const float*)d_in[0];
    const float* img2 = (const float*)d_in[1];
    float* out = (float*)d_out;

    // ws layout: [0..7] flags, [8..15] double sum, [16..] per-task partials
    unsigned* flags = (unsigned*)d_ws;
    double* sum = (double*)((char*)d_ws + 8);
    double* partials = (double*)((char*)d_ws + 16);
    int use_partials = (ws_size >= 16 + (size_t)NTASKS * sizeof(double)) ? 1 : 0;

    hipMemsetAsync(d_ws, 0, 16, stream);

    // Gaussian taps (float64 math then cast, matching numpy reference)
    GaussW gw;
    {
        double g[WS], ssum = 0.0;
        for (int i = 0; i < WS; ++i) {
            double x = (double)(i - WS / 2);
            g[i] = exp(-(x * x) / (2.0 * 1.5 * 1.5));
            ssum += g[i];
        }
        for (int i = 0; i < WS; ++i) gw.g[i] = (float)(g[i] / ssum);
    }

    int n = in_sizes[0];           // 25,165,824 floats
    flags_kernel<<<2048, 256, 0, stream>>>(img1, flags, n / 4);

    ssim_kernel<<<NBLK, 256, 0, stream>>>(img1, img2, flags, sum, partials, use_partials, gw);

    reduce_kernel<<<1, 256, 0, stream>>>(sum, partials, use_partials, out);
}

// Round 7
// 175.558 us; speedup vs baseline: 10.5674x; 1.1396x over previous
//
#include <hip/hip_runtime.h>
#include <cmath>

#define WS 11
#define IMH 512
#define IMW 512
#define OH 502
#define OW 502
#define NPLANES 96                 // 32 * 3
#define STRIPW 48                  // output cols per wave strip
#define STRIPH 64                  // output rows per wave strip (4 subs x 16)
#define SUBH 16                    // rows per lane
#define XSTRIPS 11                 // ceil(502/48)
#define YSTRIPS 8                  // ceil(502/64)
#define NTASKS (XSTRIPS * YSTRIPS * NPLANES)   // 8448
#define WPB 2                      // waves per block (128 threads)
#define NBLK (NTASKS / WPB)        // 4224
#define NOUT ((long long)NPLANES * OH * OW)    // 24192384

typedef float f32x4 __attribute__((ext_vector_type(4)));

struct GaussW { float g[WS]; };

// ---------------- kernel 1: range-detection flags over img1 ----------------
__global__ __launch_bounds__(256) void flags_kernel(const float* __restrict__ img1,
                                                    unsigned* __restrict__ flags,
                                                    int n4) {
    int idx = blockIdx.x * blockDim.x + threadIdx.x;
    int stride = gridDim.x * blockDim.x;
    int gt = 0, lt = 0;
    const float4* p = reinterpret_cast<const float4*>(img1);
    for (int i = idx; i < n4; i += stride) {
        float4 v = p[i];
        gt |= (v.x > 128.f) | (v.y > 128.f) | (v.z > 128.f) | (v.w > 128.f);
        lt |= (v.x < -0.5f) | (v.y < -0.5f) | (v.z < -0.5f) | (v.w < -0.5f);
    }
    if (gt) atomicOr(&flags[0], 1u);
    if (lt) atomicOr(&flags[1], 1u);
}

// ---------------- kernel 2: LDS-free register-ring SSIM, 4-quantity form ----
// Wave = one 48x64 output strip. Lane (g = lane&15, s = lane>>4) streams
// input col-group [4g..4g+3] down 16 rows with an 11-row register ring
// holding s = x+y and d = x-y. Vertical conv of {s, d, s^2, d^2}; horizontal
// via __shfl. SSIM terms recovered algebraically:
//   conv(s) = mu1+mu2, conv(d) = mu1-mu2,
//   P-Q = 4 E[xy], P+Q = 2(E[x^2]+E[y^2]).
__global__ __launch_bounds__(128) void ssim_kernel(const float* __restrict__ img1,
                                                   const float* __restrict__ img2,
                                                   const unsigned* __restrict__ flags,
                                                   double* __restrict__ sum_out,
                                                   double* __restrict__ partials,
                                                   int use_partials,
                                                   GaussW gw) {
    const int tid = threadIdx.x;
    const int wave = tid >> 6;
    const int lane = tid & 63;
    const int g = lane & 15;           // col group within strip
    const int s = lane >> 4;           // row sub within strip

    const int task = blockIdx.x * WPB + wave;
    const int plane = task / (XSTRIPS * YSTRIPS);
    const int rem = task - plane * (XSTRIPS * YSTRIPS);
    const int wy = rem / XSTRIPS;
    const int wx = rem - wy * XSTRIPS;

    const float* p1 = img1 + (size_t)plane * (IMH * IMW);
    const float* p2 = img2 + (size_t)plane * (IMH * IMW);

    const int x0 = wx * STRIPW;                     // strip's output col base
    int colbase = x0 + 4 * g;                       // this lane's input col base
    colbase = colbase <= IMW - 4 ? colbase : IMW - 4;  // clamp (masked outputs only)
    const int ys = wy * STRIPH + s * SUBH;          // first output row of this sub

    // constants from range flags
    float maxv = flags[0] ? 255.f : 1.f;
    float minv = flags[1] ? -1.f : 0.f;
    float L = maxv - minv;
    float C1 = (0.01f * L) * (0.01f * L);
    float C2 = (0.03f * L) * (0.03f * L);

    // per-lane column masks (loop-invariant)
    float cmask[4];
    #pragma unroll
    for (int c = 0; c < 4; ++c)
        cmask[c] = (g < 12 && (x0 + 4 * g + c) < OW) ? 1.f : 0.f;

    // ---- prime the 11-row ring (s,d) with rows ys .. ys+9 ----
    f32x4 rs[WS], rd[WS];
    #pragma unroll
    for (int k = 0; k < WS - 1; ++k) {
        int row = ys + k; row = row < IMH - 1 ? row : IMH - 1;
        const float* r1 = p1 + (size_t)row * IMW + colbase;
        const float* r2 = p2 + (size_t)row * IMW + colbase;
        f32x4 a = *reinterpret_cast<const f32x4*>(r1);
        f32x4 b = *reinterpret_cast<const f32x4*>(r2);
        rs[k] = a + b;
        rd[k] = a - b;
    }

    float local = 0.f;

    for (int i = 0; i < SUBH; ++i) {
        // load row ys+i+10 into ring slot 10
        {
            int row = ys + i + (WS - 1); row = row < IMH - 1 ? row : IMH - 1;
            const float* r1 = p1 + (size_t)row * IMW + colbase;
            const float* r2 = p2 + (size_t)row * IMW + colbase;
            f32x4 a = *reinterpret_cast<const f32x4*>(r1);
            f32x4 b = *reinterpret_cast<const f32x4*>(r2);
            rs[WS - 1] = a + b;
            rd[WS - 1] = a - b;
        }

        // ---- vertical 11-tap conv of {s, d, s^2, d^2} (registers only) ----
        f32x4 S = 0.f, D = 0.f, P = 0.f, Q = 0.f;
        #pragma unroll
        for (int k = 0; k < WS; ++k) {
            float w = gw.g[k];
            f32x4 sv = rs[k], dv = rd[k];
            S += w * sv;
            D += w * dv;
            P += w * (sv * sv);
            Q += w * (dv * dv);
        }

        // ---- shift ring ----
        #pragma unroll
        for (int k = 0; k < WS - 1; ++k) { rs[k] = rs[k + 1]; rd[k] = rd[k + 1]; }

        // ---- horizontal 11-tap conv via cross-lane shuffles (4 quantities) ----
        float hs[4][4];
        #pragma unroll
        for (int q = 0; q < 4; ++q) {
            f32x4 v = (q == 0) ? S : (q == 1) ? D : (q == 2) ? P : Q;
            float Wq[14];
            #pragma unroll
            for (int j = 0; j < 4; ++j) Wq[j] = v[j];
            #pragma unroll
            for (int j = 0; j < 4; ++j) Wq[4 + j]  = __shfl(v[j], lane + 1, 64);
            #pragma unroll
            for (int j = 0; j < 4; ++j) Wq[8 + j]  = __shfl(v[j], lane + 2, 64);
            #pragma unroll
            for (int j = 0; j < 2; ++j) Wq[12 + j] = __shfl(v[j], lane + 3, 64);
            #pragma unroll
            for (int c = 0; c < 4; ++c) {
                float acc = 0.f;
                #pragma unroll
                for (int k = 0; k < WS; ++k) acc += gw.g[k] * Wq[c + k];
                hs[q][c] = acc;
            }
        }

        // ---- SSIM map from 4-quantity form + masked accumulate ----
        const int oy = ys + i;
        float rowm = (oy < OH) ? 1.f : 0.f;
        #pragma unroll
        for (int c = 0; c < 4; ++c) {
            float hS = hs[0][c], hD = hs[1][c], Pv = hs[2][c], Qv = hs[3][c];
            float hS2 = hS * hS, hD2 = hD * hD;
            float mu12_2 = (hS2 - hD2) * 0.5f;   // 2*mu1*mu2
            float msq    = (hS2 + hD2) * 0.5f;   // mu1^2 + mu2^2
            float exy2   = (Pv - Qv) * 0.5f;     // 2*E[xy]
            float es     = (Pv + Qv) * 0.5f;     // E[x^2] + E[y^2]
            float v1 = (exy2 - mu12_2) + C2;     // 2*sigma12 + C2
            float v2 = (es - msq) + C2;          // sigma1+sigma2 + C2
            float num = (mu12_2 + C1) * v1;
            float den = (msq + C1) * v2;
            float rc = __builtin_amdgcn_rcpf(den);
            rc = rc * (2.0f - den * rc);         // 1 Newton step
            local = fmaf(num * rc, cmask[c] * rowm, local);
        }
    }

    // ---- wave reduction -> one double per task ----
    #pragma unroll
    for (int off = 32; off > 0; off >>= 1)
        local += __shfl_down(local, off, 64);

    if (lane == 0) {
        if (use_partials) partials[task] = (double)local;
        else atomicAdd(sum_out, (double)local);
    }
}

// ---------------- kernel 3: final reduce + mean ----------------
__global__ __launch_bounds__(256) void reduce_kernel(const double* __restrict__ sum,
                                                     const double* __restrict__ partials,
                                                     int use_partials,
                                                     float* __restrict__ out) {
    if (use_partials) {
        double local = 0.0;
        for (int i = threadIdx.x; i < NTASKS; i += 256) local += partials[i];
        #pragma unroll
        for (int off = 32; off > 0; off >>= 1)
            local += __shfl_down(local, off, 64);
        __shared__ double ws2[4];
        int wave = threadIdx.x >> 6, lane = threadIdx.x & 63;
        if (lane == 0) ws2[wave] = local;
        __syncthreads();
        if (threadIdx.x == 0)
            out[0] = (float)((ws2[0] + ws2[1] + ws2[2] + ws2[3]) / (double)NOUT);
    } else {
        if (threadIdx.x == 0) out[0] = (float)(sum[0] / (double)NOUT);
    }
}

extern "C" void kernel_launch(void* const* d_in, const int* in_sizes, int n_in,
                              void* d_out, int out_size, void* d_ws, size_t ws_size,
                              hipStream_t stream) {
    const float* img1 = (const float*)d_in[0];
    const float* img2 = (const float*)d_in[1];
    float* out = (float*)d_out;

    // ws layout: [0..7] flags, [8..15] double sum, [16..] per-task partials
    unsigned* flags = (unsigned*)d_ws;
    double* sum = (double*)((char*)d_ws + 8);
    double* partials = (double*)((char*)d_ws + 16);
    int use_partials = (ws_size >= 16 + (size_t)NTASKS * sizeof(double)) ? 1 : 0;

    hipMemsetAsync(d_ws, 0, 16, stream);

    // Gaussian taps (float64 math then cast, matching numpy reference)
    GaussW gw;
    {
        double g[WS], ssum = 0.0;
        for (int i = 0; i < WS; ++i) {
            double x = (double)(i - WS / 2);
            g[i] = exp(-(x * x) / (2.0 * 1.5 * 1.5));
            ssum += g[i];
        }
        for (int i = 0; i < WS; ++i) gw.g[i] = (float)(g[i] / ssum);
    }

    int n = in_sizes[0];           // 25,165,824 floats
    flags_kernel<<<2048, 256, 0, stream>>>(img1, flags, n / 4);

    ssim_kernel<<<NBLK, 128, 0, stream>>>(img1, img2, flags, sum, partials, use_partials, gw);

    reduce_kernel<<<1, 256, 0, stream>>>(sum, partials, use_partials, out);
}

// Round 8
// 145.368 us; speedup vs baseline: 12.7620x; 1.2077x over previous
//
#include <hip/hip_runtime.h>
#include <cmath>

#define WS 11
#define IMH 512
#define IMW 512
#define OH 502
#define OW 502
#define NPLANES 96                 // 32 * 3
#define STRIPW 48                  // output cols per wave strip
#define STRIPH 64                  // output rows per wave strip (4 subs x 16)
#define SUBH 16                    // rows per lane
#define XSTRIPS 11                 // ceil(502/48)
#define YSTRIPS 8                  // ceil(502/64)
#define NTASKS (XSTRIPS * YSTRIPS * NPLANES)   // 8448
#define WPB 2                      // waves per block (128 threads)
#define NBLK (NTASKS / WPB)        // 4224
#define NOUT ((long long)NPLANES * OH * OW)    // 24192384

typedef float f32x4 __attribute__((ext_vector_type(4)));

struct GaussW { float g[WS]; };

// ---------------- kernel 1: range-detection flags over img1 ----------------
__global__ __launch_bounds__(256) void flags_kernel(const float* __restrict__ img1,
                                                    unsigned* __restrict__ flags,
                                                    int n4) {
    int idx = blockIdx.x * blockDim.x + threadIdx.x;
    int stride = gridDim.x * blockDim.x;
    int gt = 0, lt = 0;
    const float4* p = reinterpret_cast<const float4*>(img1);
    for (int i = idx; i < n4; i += stride) {
        float4 v = p[i];
        gt |= (v.x > 128.f) | (v.y > 128.f) | (v.z > 128.f) | (v.w > 128.f);
        lt |= (v.x < -0.5f) | (v.y < -0.5f) | (v.z < -0.5f) | (v.w < -0.5f);
    }
    if (gt) atomicOr(&flags[0], 1u);
    if (lt) atomicOr(&flags[1], 1u);
}

// ---------------- kernel 2: LDS-free register-ring SSIM, 4-quantity form ----
// Wave = one 48x64 output strip. Lane (g = lane&15, s = lane>>4) streams
// input col-group [4g..4g+3] down 16 rows with an 11-row register ring
// holding s = x+y and d = x-y. The row loop is FULLY UNROLLED so the ring
// lives in registers (static indices, shifts become SSA renames) and each
// iteration issues exactly 2 global b128 loads.
__global__ __launch_bounds__(128) void ssim_kernel(const float* __restrict__ img1,
                                                   const float* __restrict__ img2,
                                                   const unsigned* __restrict__ flags,
                                                   double* __restrict__ sum_out,
                                                   double* __restrict__ partials,
                                                   int use_partials,
                                                   GaussW gw) {
    const int tid = threadIdx.x;
    const int wave = tid >> 6;
    const int lane = tid & 63;
    const int g = lane & 15;           // col group within strip
    const int s = lane >> 4;           // row sub within strip

    const int task = blockIdx.x * WPB + wave;
    const int plane = task / (XSTRIPS * YSTRIPS);
    const int rem = task - plane * (XSTRIPS * YSTRIPS);
    const int wy = rem / XSTRIPS;
    const int wx = rem - wy * XSTRIPS;

    const float* p1 = img1 + (size_t)plane * (IMH * IMW);
    const float* p2 = img2 + (size_t)plane * (IMH * IMW);

    const int x0 = wx * STRIPW;                     // strip's output col base
    int colbase = x0 + 4 * g;                       // this lane's input col base
    colbase = colbase <= IMW - 4 ? colbase : IMW - 4;  // clamp (masked outputs only)
    const int ys = wy * STRIPH + s * SUBH;          // first output row of this sub

    // constants from range flags
    float maxv = flags[0] ? 255.f : 1.f;
    float minv = flags[1] ? -1.f : 0.f;
    float L = maxv - minv;
    float C1 = (0.01f * L) * (0.01f * L);
    float C2 = (0.03f * L) * (0.03f * L);

    // ---- prime the 11-row ring (s,d) with rows ys .. ys+9 ----
    f32x4 rs[WS], rd[WS];
    #pragma unroll
    for (int k = 0; k < WS - 1; ++k) {
        int row = ys + k; row = row < IMH - 1 ? row : IMH - 1;
        const float* r1 = p1 + (size_t)row * IMW + colbase;
        const float* r2 = p2 + (size_t)row * IMW + colbase;
        f32x4 a = *reinterpret_cast<const f32x4*>(r1);
        f32x4 b = *reinterpret_cast<const f32x4*>(r2);
        rs[k] = a + b;
        rd[k] = a - b;
    }

    f32x4 acc4 = 0.f;    // per-column accumulators; masks applied after loop

    #pragma unroll
    for (int i = 0; i < SUBH; ++i) {
        // load row ys+i+10 into ring slot 10
        {
            int row = ys + i + (WS - 1); row = row < IMH - 1 ? row : IMH - 1;
            const float* r1 = p1 + (size_t)row * IMW + colbase;
            const float* r2 = p2 + (size_t)row * IMW + colbase;
            f32x4 a = *reinterpret_cast<const f32x4*>(r1);
            f32x4 b = *reinterpret_cast<const f32x4*>(r2);
            rs[WS - 1] = a + b;
            rd[WS - 1] = a - b;
        }

        // ---- vertical 11-tap conv of {s, d, s^2, d^2} (registers only) ----
        f32x4 S = 0.f, D = 0.f, P = 0.f, Q = 0.f;
        #pragma unroll
        for (int k = 0; k < WS; ++k) {
            float w = gw.g[k];
            f32x4 sv = rs[k], dv = rd[k];
            S += w * sv;
            D += w * dv;
            P += w * (sv * sv);
            Q += w * (dv * dv);
        }

        // ---- shift ring (SSA renames after full unroll) ----
        #pragma unroll
        for (int k = 0; k < WS - 1; ++k) { rs[k] = rs[k + 1]; rd[k] = rd[k + 1]; }

        // ---- horizontal 11-tap conv via cross-lane shuffles (4 quantities) ----
        float hs[4][4];
        #pragma unroll
        for (int q = 0; q < 4; ++q) {
            f32x4 v = (q == 0) ? S : (q == 1) ? D : (q == 2) ? P : Q;
            float Wq[14];
            #pragma unroll
            for (int j = 0; j < 4; ++j) Wq[j] = v[j];
            #pragma unroll
            for (int j = 0; j < 4; ++j) Wq[4 + j]  = __shfl(v[j], lane + 1, 64);
            #pragma unroll
            for (int j = 0; j < 4; ++j) Wq[8 + j]  = __shfl(v[j], lane + 2, 64);
            #pragma unroll
            for (int j = 0; j < 2; ++j) Wq[12 + j] = __shfl(v[j], lane + 3, 64);
            #pragma unroll
            for (int c = 0; c < 4; ++c) {
                float acc = 0.f;
                #pragma unroll
                for (int k = 0; k < WS; ++k) acc += gw.g[k] * Wq[c + k];
                hs[q][c] = acc;
            }
        }

        // ---- SSIM map from 4-quantity form; row-masked accumulate ----
        const int oy = ys + i;
        float rowm = (oy < OH) ? 1.f : 0.f;
        #pragma unroll
        for (int c = 0; c < 4; ++c) {
            float hS = hs[0][c], hD = hs[1][c], Pv = hs[2][c], Qv = hs[3][c];
            float hS2 = hS * hS, hD2 = hD * hD;
            float mu12_2 = (hS2 - hD2) * 0.5f;   // 2*mu1*mu2
            float msq    = (hS2 + hD2) * 0.5f;   // mu1^2 + mu2^2
            float exy2   = (Pv - Qv) * 0.5f;     // 2*E[xy]
            float es     = (Pv + Qv) * 0.5f;     // E[x^2] + E[y^2]
            float v1 = (exy2 - mu12_2) + C2;     // 2*sigma12 + C2
            float v2 = (es - msq) + C2;          // sigma1+sigma2 + C2
            float num = (mu12_2 + C1) * v1;
            float den = (msq + C1) * v2;
            float rc = __builtin_amdgcn_rcpf(den);   // ~1 ulp, no Newton needed
            acc4[c] = fmaf(num * rc, rowm, acc4[c]);
        }
    }

    // ---- apply column masks once, then wave reduction ----
    float local = 0.f;
    #pragma unroll
    for (int c = 0; c < 4; ++c) {
        float cm = (g < 12 && (x0 + 4 * g + c) < OW) ? 1.f : 0.f;
        local = fmaf(acc4[c], cm, local);
    }

    #pragma unroll
    for (int off = 32; off > 0; off >>= 1)
        local += __shfl_down(local, off, 64);

    if (lane == 0) {
        if (use_partials) partials[task] = (double)local;
        else atomicAdd(sum_out, (double)local);
    }
}

// ---------------- kernel 3: final reduce + mean ----------------
__global__ __launch_bounds__(256) void reduce_kernel(const double* __restrict__ sum,
                                                     const double* __restrict__ partials,
                                                     int use_partials,
                                                     float* __restrict__ out) {
    if (use_partials) {
        double local = 0.0;
        for (int i = threadIdx.x; i < NTASKS; i += 256) local += partials[i];
        #pragma unroll
        for (int off = 32; off > 0; off >>= 1)
            local += __shfl_down(local, off, 64);
        __shared__ double ws2[4];
        int wave = threadIdx.x >> 6, lane = threadIdx.x & 63;
        if (lane == 0) ws2[wave] = local;
        __syncthreads();
        if (threadIdx.x == 0)
            out[0] = (float)((ws2[0] + ws2[1] + ws2[2] + ws2[3]) / (double)NOUT);
    } else {
        if (threadIdx.x == 0) out[0] = (float)(sum[0] / (double)NOUT);
    }
}

extern "C" void kernel_launch(void* const* d_in, const int* in_sizes, int n_in,
                              void* d_out, int out_size, void* d_ws, size_t ws_size,
                              hipStream_t stream) {
    const float* img1 = (const float*)d_in[0];
    const float* img2 = (const float*)d_in[1];
    float* out = (float*)d_out;

    // ws layout: [0..7] flags, [8..15] double sum, [16..] per-task partials
    unsigned* flags = (unsigned*)d_ws;
    double* sum = (double*)((char*)d_ws + 8);
    double* partials = (double*)((char*)d_ws + 16);
    int use_partials = (ws_size >= 16 + (size_t)NTASKS * sizeof(double)) ? 1 : 0;

    hipMemsetAsync(d_ws, 0, 16, stream);

    // Gaussian taps (float64 math then cast, matching numpy reference)
    GaussW gw;
    {
        double g[WS], ssum = 0.0;
        for (int i = 0; i < WS; ++i) {
            double x = (double)(i - WS / 2);
            g[i] = exp(-(x * x) / (2.0 * 1.5 * 1.5));
            ssum += g[i];
        }
        for (int i = 0; i < WS; ++i) gw.g[i] = (float)(g[i] / ssum);
    }

    int n = in_sizes[0];           // 25,165,824 floats
    flags_kernel<<<2048, 256, 0, stream>>>(img1, flags, n / 4);

    ssim_kernel<<<NBLK, 128, 0, stream>>>(img1, img2, flags, sum, partials, use_partials, gw);

    reduce_kernel<<<1, 256, 0, stream>>>(sum, partials, use_partials, out);
}